// Round 3
// baseline (218.156 us; speedup 1.0000x reference)
//
#include <hip/hip_runtime.h>
#include <math.h>

#define NBINS 32
#define NB2   1024      // 32*32
#define EPSD  1e-8

// ws layout:
//   [0,    4096) : uint   ghist[1024]   (global joint histogram)
//   [4096, 4104) : double gent          (entropy sum)
//   [4104, 4108) : uint   gcnt          (high-conf count)
// ws is poisoned 0xAA before every launch -> zero_kernel initializes it.

__device__ inline double block_reduce_sum_d(double v, double* sh) {
#pragma unroll
    for (int o = 32; o > 0; o >>= 1) v += __shfl_down(v, o, 64);
    const int lane = threadIdx.x & 63;
    const int wave = threadIdx.x >> 6;
    const int nw   = blockDim.x >> 6;
    __syncthreads();
    if (lane == 0) sh[wave] = v;
    __syncthreads();
    double r = (threadIdx.x < nw) ? sh[threadIdx.x] : 0.0;
    if (wave == 0) {
#pragma unroll
        for (int o = 8; o > 0; o >>= 1) r += __shfl_down(r, o, 64);
    }
    return r;  // valid in thread 0
}

extern "C" __global__ void __launch_bounds__(1024)
topo_zero_kernel(unsigned int* __restrict__ ghist,
                 double* __restrict__ gent,
                 unsigned int* __restrict__ gcnt)
{
    ghist[threadIdx.x] = 0u;
    if (threadIdx.x == 0) { *gent = 0.0; *gcnt = 0u; }
}

__device__ inline void process4(float4 s, float4 t, float4 u,
                                unsigned int* myh, float& ent, unsigned int& cnt)
{
    float sv[4] = {s.x, s.y, s.z, s.w};
    float tv[4] = {t.x, t.y, t.z, t.w};
    float uv[4] = {u.x, u.y, u.z, u.w};
#pragma unroll
    for (int k = 0; k < 4; ++k) {
        float topo = 1.0f - fabsf(sv[k] - tv[k]);   // (0, 1]
        float conf = 1.0f - uv[k];                  // (0, 1]
        int ti = (int)(topo * 32.0f);               // exact binning (edges = k/32)
        int ci = (int)(conf * 32.0f);
        if (ti < NBINS && ci < NBINS)
            atomicAdd(&myh[(ti << 5) + ci], 1u);
        bool hc = conf > 0.8f;
        float tc = fminf(fmaxf(topo, 1e-8f), 1.0f - 1e-8f);
        float e  = -tc * __logf(tc + 1e-8f);
        ent += hc ? e : 0.0f;
        cnt += hc ? 1u : 0u;
    }
}

extern "C" __global__ void __launch_bounds__(256)
topo_hist_kernel(const float* __restrict__ stu, const float* __restrict__ tea,
                 const float* __restrict__ unc,
                 unsigned int* __restrict__ ghist,
                 double* __restrict__ gent,
                 unsigned int* __restrict__ gcnt,
                 int n)
{
    __shared__ unsigned int sh_hist[4 * NB2];   // one 1024-bin sub-hist per wave
    __shared__ double sh_red[4];

    const int wave = threadIdx.x >> 6;
    unsigned int* myh = sh_hist + wave * NB2;

    for (int i = threadIdx.x; i < 4 * NB2; i += blockDim.x) sh_hist[i] = 0u;
    __syncthreads();

    float ent = 0.0f;          // <=32 elems/thread, values <=0.37 -> f32 is plenty
    unsigned int cnt = 0;

    const int n4     = n >> 2;
    const int gid    = blockIdx.x * blockDim.x + threadIdx.x;
    const int stride = gridDim.x * blockDim.x;

    const float4* s4 = (const float4*)stu;
    const float4* t4 = (const float4*)tea;
    const float4* u4 = (const float4*)unc;

    int i = gid;
    // 2x unrolled: issue all 6 loads before processing (ILP / latency hiding)
    for (; i + stride < n4; i += 2 * stride) {
        float4 s0 = s4[i];          float4 s1 = s4[i + stride];
        float4 t0 = t4[i];          float4 t1 = t4[i + stride];
        float4 u0 = u4[i];          float4 u1 = u4[i + stride];
        process4(s0, t0, u0, myh, ent, cnt);
        process4(s1, t1, u1, myh, ent, cnt);
    }
    for (; i < n4; i += stride) {
        process4(s4[i], t4[i], u4[i], myh, ent, cnt);
    }
    // scalar tail (no-op for 4096^2)
    for (int j = (n4 << 2) + gid; j < n; j += stride) {
        float topo = 1.0f - fabsf(stu[j] - tea[j]);
        float conf = 1.0f - unc[j];
        int ti = (int)(topo * 32.0f);
        int ci = (int)(conf * 32.0f);
        if (ti < NBINS && ci < NBINS)
            atomicAdd(&myh[(ti << 5) + ci], 1u);
        if (conf > 0.8f) {
            float tc = fminf(fmaxf(topo, 1e-8f), 1.0f - 1e-8f);
            ent += -tc * __logf(tc + 1e-8f);
            cnt++;
        }
    }

    __syncthreads();
    // flush: sum 4 sub-hists, one global atomic per bin
    for (int b = threadIdx.x; b < NB2; b += blockDim.x) {
        unsigned int v = sh_hist[b] + sh_hist[NB2 + b] +
                         sh_hist[2 * NB2 + b] + sh_hist[3 * NB2 + b];
        if (v) atomicAdd(&ghist[b], v);
    }

    double es = block_reduce_sum_d((double)ent, sh_red);
    double cs = block_reduce_sum_d((double)cnt, sh_red);
    if (threadIdx.x == 0) {
        atomicAdd(gent, es);
        atomicAdd(gcnt, (unsigned int)(cs + 0.5));
    }
}

extern "C" __global__ void __launch_bounds__(1024)
topo_final_kernel(const unsigned int* __restrict__ ghist,
                  const double* __restrict__ gent,
                  const unsigned int* __restrict__ gcnt,
                  float* __restrict__ out)
{
    __shared__ double sh_red[16];
    __shared__ double jp[NB2];
    __shared__ double marg_r[NBINS];
    __shared__ double marg_c[NBINS];
    __shared__ double bcast;

    const int tid = threadIdx.x;

    double dc = (double)ghist[tid];

    double total = block_reduce_sum_d(dc, sh_red);
    if (tid == 0) bcast = total;
    __syncthreads();
    total = bcast;

    double p = dc / (total + EPSD);
    jp[tid] = p;
    __syncthreads();

    if (tid < NBINS) {
        double s = 0.0;
        for (int cc = 0; cc < NBINS; ++cc) s += jp[(tid << 5) + cc];
        marg_r[tid] = s;
    } else if (tid < 2 * NBINS) {
        int cc = tid - NBINS;
        double s = 0.0;
        for (int r = 0; r < NBINS; ++r) s += jp[(r << 5) + cc];
        marg_c[cc] = s;
    }
    __syncthreads();

    const int r  = tid >> 5;
    const int cc = tid & 31;
    double term = 0.0;
    if (p > EPSD)
        term = p * log(p / (marg_r[r] * marg_c[cc] + EPSD) + EPSD);
    double mi = block_reduce_sum_d(term, sh_red);

    if (tid == 0) {
        double es = *gent;
        double cs = (double)(*gcnt);
        double mi_v     = (total < EPSD) ? 0.0 : mi;
        double mean     = es / fmax(cs, 1.0);
        double ent_loss = (cs > 10.0) ? mean : 0.0;
        out[0] = (float)(-mi_v + 0.1 * ent_loss);
    }
}

extern "C" void kernel_launch(void* const* d_in, const int* in_sizes, int n_in,
                              void* d_out, int out_size, void* d_ws, size_t ws_size,
                              hipStream_t stream) {
    const float* stu = (const float*)d_in[0];
    const float* tea = (const float*)d_in[1];
    const float* unc = (const float*)d_in[2];
    float* out = (float*)d_out;
    int n = in_sizes[0];

    unsigned int* ghist = (unsigned int*)d_ws;
    double*       gent  = (double*)((char*)d_ws + 4096);
    unsigned int* gcnt  = (unsigned int*)((char*)d_ws + 4104);

    const int B = 2048;  // 8 blocks/CU: LDS 8*16.9KB=135KB<160KB, 32 waves/CU = 100% nominal

    topo_zero_kernel<<<1, 1024, 0, stream>>>(ghist, gent, gcnt);
    topo_hist_kernel<<<B, 256, 0, stream>>>(stu, tea, unc, ghist, gent, gcnt, n);
    topo_final_kernel<<<1, 1024, 0, stream>>>(ghist, gent, gcnt, out);
}

// Round 4
// 211.969 us; speedup vs baseline: 1.0292x; 1.0292x over previous
//
#include <hip/hip_runtime.h>
#include <math.h>

#define NBINS 32
#define NB2   1024      // 32*32
#define EPSD  1e-8
#define MAXB  1024

// ws layout (all slots written unconditionally every launch -> no zero-init):
//   [0,       4 MB) : uint   hist_part[1024][1024]  per-block histograms
//   [4 MB, +128 KB) : uint   partial2[32][1024]     stage-1 reduced histograms
//   next    8 KB    : double ent_part[1024]
//   next    4 KB    : uint   cnt_part[1024]

#define OFF_P2   (MAXB * NB2 * sizeof(unsigned int))          // 4 MB
#define OFF_ENT  (OFF_P2 + 32 * NB2 * sizeof(unsigned int))   // +128 KB
#define OFF_CNT  (OFF_ENT + MAXB * sizeof(double))            // +8 KB
#define WS_NEED  (OFF_CNT + MAXB * sizeof(unsigned int))

__device__ inline double block_reduce_sum_d(double v, double* sh) {
#pragma unroll
    for (int o = 32; o > 0; o >>= 1) v += __shfl_down(v, o, 64);
    const int lane = threadIdx.x & 63;
    const int wave = threadIdx.x >> 6;
    const int nw   = blockDim.x >> 6;
    __syncthreads();
    if (lane == 0) sh[wave] = v;
    __syncthreads();
    double r = (threadIdx.x < nw) ? sh[threadIdx.x] : 0.0;
    if (wave == 0) {
#pragma unroll
        for (int o = 8; o > 0; o >>= 1) r += __shfl_down(r, o, 64);
    }
    return r;  // valid in thread 0
}

__device__ inline void process4(float4 s, float4 t, float4 u,
                                unsigned int* myh, float& ent, unsigned int& cnt)
{
    float sv[4] = {s.x, s.y, s.z, s.w};
    float tv[4] = {t.x, t.y, t.z, t.w};
    float uv[4] = {u.x, u.y, u.z, u.w};
#pragma unroll
    for (int k = 0; k < 4; ++k) {
        float topo = 1.0f - fabsf(sv[k] - tv[k]);   // (0, 1]
        float conf = 1.0f - uv[k];                  // (0, 1]
        int ti = (int)(topo * 32.0f);               // exact binning (edges = k/32)
        int ci = (int)(conf * 32.0f);
        if (ti < NBINS && ci < NBINS)
            atomicAdd(&myh[(ti << 5) + ci], 1u);
        bool hc = conf > 0.8f;
        float tc = fminf(fmaxf(topo, 1e-8f), 1.0f - 1e-8f);
        float e  = -tc * __logf(tc + 1e-8f);
        ent += hc ? e : 0.0f;
        cnt += hc ? 1u : 0u;
    }
}

extern "C" __global__ void __launch_bounds__(256)
topo_hist_kernel(const float* __restrict__ stu, const float* __restrict__ tea,
                 const float* __restrict__ unc,
                 unsigned int* __restrict__ hist_part,
                 double* __restrict__ ent_part,
                 unsigned int* __restrict__ cnt_part,
                 int n)
{
    __shared__ unsigned int sh_hist[4 * NB2];   // one 1024-bin sub-hist per wave
    __shared__ double sh_red[4];

    const int wave = threadIdx.x >> 6;
    unsigned int* myh = sh_hist + wave * NB2;

    for (int i = threadIdx.x; i < 4 * NB2; i += blockDim.x) sh_hist[i] = 0u;
    __syncthreads();

    float ent = 0.0f;          // <=64 elems/thread, values <=0.37 -> f32 plenty
    unsigned int cnt = 0;

    const int n4     = n >> 2;
    const int gid    = blockIdx.x * blockDim.x + threadIdx.x;
    const int stride = gridDim.x * blockDim.x;

    const float4* s4 = (const float4*)stu;
    const float4* t4 = (const float4*)tea;
    const float4* u4 = (const float4*)unc;

    int i = gid;
    // 4x unrolled, all 12 loads issued before any processing (MLP).
    // For n=4096^2, B=1024: exactly 4 trips, no tail.
    for (; i + 3 * stride < n4; i += 4 * stride) {
        float4 s0 = s4[i];              float4 t0 = t4[i];              float4 u0 = u4[i];
        float4 s1 = s4[i + stride];     float4 t1 = t4[i + stride];     float4 u1 = u4[i + stride];
        float4 s2 = s4[i + 2 * stride]; float4 t2 = t4[i + 2 * stride]; float4 u2 = u4[i + 2 * stride];
        float4 s3 = s4[i + 3 * stride]; float4 t3 = t4[i + 3 * stride]; float4 u3 = u4[i + 3 * stride];
        process4(s0, t0, u0, myh, ent, cnt);
        process4(s1, t1, u1, myh, ent, cnt);
        process4(s2, t2, u2, myh, ent, cnt);
        process4(s3, t3, u3, myh, ent, cnt);
    }
    for (; i < n4; i += stride)
        process4(s4[i], t4[i], u4[i], myh, ent, cnt);
    for (int j = (n4 << 2) + gid; j < n; j += stride) {
        float topo = 1.0f - fabsf(stu[j] - tea[j]);
        float conf = 1.0f - unc[j];
        int ti = (int)(topo * 32.0f);
        int ci = (int)(conf * 32.0f);
        if (ti < NBINS && ci < NBINS)
            atomicAdd(&myh[(ti << 5) + ci], 1u);
        if (conf > 0.8f) {
            float tc = fminf(fmaxf(topo, 1e-8f), 1.0f - 1e-8f);
            ent += -tc * __logf(tc + 1e-8f);
            cnt++;
        }
    }

    __syncthreads();
    // non-atomic flush: plain coalesced stores of this block's 1024-bin hist
    for (int b = threadIdx.x; b < NB2; b += blockDim.x) {
        unsigned int v = sh_hist[b] + sh_hist[NB2 + b] +
                         sh_hist[2 * NB2 + b] + sh_hist[3 * NB2 + b];
        hist_part[(size_t)blockIdx.x * NB2 + b] = v;
    }

    double es = block_reduce_sum_d((double)ent, sh_red);
    double cs = block_reduce_sum_d((double)cnt, sh_red);
    if (threadIdx.x == 0) {
        ent_part[blockIdx.x] = es;
        cnt_part[blockIdx.x] = cs;   // store as double? no—uint slot; cast below
    }
    if (threadIdx.x == 0) cnt_part[blockIdx.x] = (unsigned int)(cs + 0.5);
}

// stage-1 reduce: 128 blocks x 256 threads; block g: slice s=g>>2, bin chunk c=g&3
extern "C" __global__ void __launch_bounds__(256)
topo_reduce_kernel(const unsigned int* __restrict__ hist_part,
                   unsigned int* __restrict__ partial2, int B)
{
    const int g   = blockIdx.x;
    const int s   = g >> 2;
    const int c   = g & 3;
    const int bin = (c << 8) + threadIdx.x;
    unsigned int acc = 0;
    for (int b = s; b < B; b += 32)
        acc += hist_part[(size_t)b * NB2 + bin];
    partial2[s * NB2 + bin] = acc;
}

extern "C" __global__ void __launch_bounds__(1024)
topo_final_kernel(const unsigned int* __restrict__ partial2,
                  const double* __restrict__ ent_part,
                  const unsigned int* __restrict__ cnt_part,
                  int B, float* __restrict__ out)
{
    __shared__ double sh_red[16];
    __shared__ double jp[NB2];
    __shared__ double marg_r[NBINS];
    __shared__ double marg_c[NBINS];
    __shared__ double bcast;

    const int tid = threadIdx.x;

    unsigned int c = 0;
#pragma unroll
    for (int s = 0; s < 32; ++s) c += partial2[s * NB2 + tid];
    double dc = (double)c;

    double total = block_reduce_sum_d(dc, sh_red);
    if (tid == 0) bcast = total;
    __syncthreads();
    total = bcast;

    double p = dc / (total + EPSD);
    jp[tid] = p;
    __syncthreads();

    if (tid < NBINS) {
        double s = 0.0;
        for (int cc = 0; cc < NBINS; ++cc) s += jp[(tid << 5) + cc];
        marg_r[tid] = s;
    } else if (tid < 2 * NBINS) {
        int cc = tid - NBINS;
        double s = 0.0;
        for (int r = 0; r < NBINS; ++r) s += jp[(r << 5) + cc];
        marg_c[cc] = s;
    }
    __syncthreads();

    const int r  = tid >> 5;
    const int cc = tid & 31;
    double term = 0.0;
    if (p > EPSD)
        term = p * log(p / (marg_r[r] * marg_c[cc] + EPSD) + EPSD);
    double mi = block_reduce_sum_d(term, sh_red);

    double ev = (tid < B) ? ent_part[tid] : 0.0;
    double es = block_reduce_sum_d(ev, sh_red);
    double cv = (tid < B) ? (double)cnt_part[tid] : 0.0;
    double cs = block_reduce_sum_d(cv, sh_red);

    if (tid == 0) {
        double mi_v     = (total < EPSD) ? 0.0 : mi;
        double mean     = es / fmax(cs, 1.0);
        double ent_loss = (cs > 10.0) ? mean : 0.0;
        out[0] = (float)(-mi_v + 0.1 * ent_loss);
    }
}

extern "C" void kernel_launch(void* const* d_in, const int* in_sizes, int n_in,
                              void* d_out, int out_size, void* d_ws, size_t ws_size,
                              hipStream_t stream) {
    const float* stu = (const float*)d_in[0];
    const float* tea = (const float*)d_in[1];
    const float* unc = (const float*)d_in[2];
    float* out = (float*)d_out;
    int n = in_sizes[0];

    int B = MAXB;  // 1024 blocks x 256 = 4 blocks/CU (R2's faster config)
    if (ws_size < WS_NEED) {
        // shrink B to fit (keeps layout offsets valid since they're MAXB-based only
        // for hist_part sizing; recompute conservatively)
        size_t per = NB2 * sizeof(unsigned int);
        size_t fixed = 32 * NB2 * sizeof(unsigned int) + MAXB * (sizeof(double) + sizeof(unsigned int));
        B = (ws_size > fixed) ? (int)((ws_size - fixed) / per) : 1;
        if (B < 1) B = 1;
        if (B > MAXB) B = MAXB;
    }

    unsigned int* hist_part = (unsigned int*)d_ws;
    unsigned int* partial2  = (unsigned int*)((char*)d_ws + OFF_P2);
    double*       ent_part  = (double*)((char*)d_ws + OFF_ENT);
    unsigned int* cnt_part  = (unsigned int*)((char*)d_ws + OFF_CNT);

    topo_hist_kernel<<<B, 256, 0, stream>>>(stu, tea, unc, hist_part, ent_part, cnt_part, n);
    topo_reduce_kernel<<<128, 256, 0, stream>>>(hist_part, partial2, B);
    topo_final_kernel<<<1, 1024, 0, stream>>>(partial2, ent_part, cnt_part, B, out);
}

// Round 5
// 209.905 us; speedup vs baseline: 1.0393x; 1.0098x over previous
//
#include <hip/hip_runtime.h>
#include <math.h>

#define NBINS 32
#define NB2   1024      // 32*32
#define EPSD  1e-8
#define MAXB  1024

// ws layout (all slots written unconditionally every launch -> no zero-init):
//   [0,       4 MB) : uint   hist_part[1024][1024]  per-block histograms
//   [4 MB, +128 KB) : uint   partial2[32][1024]     stage-1 reduced histograms
//   next    8 KB    : double ent_part[1024]
//   next    4 KB    : uint   cnt_part[1024]

#define OFF_P2   (MAXB * NB2 * sizeof(unsigned int))          // 4 MB
#define OFF_ENT  (OFF_P2 + 32 * NB2 * sizeof(unsigned int))   // +128 KB
#define OFF_CNT  (OFF_ENT + MAXB * sizeof(double))            // +8 KB
#define WS_NEED  (OFF_CNT + MAXB * sizeof(unsigned int))

__device__ inline double block_reduce_sum_d(double v, double* sh) {
#pragma unroll
    for (int o = 32; o > 0; o >>= 1) v += __shfl_down(v, o, 64);
    const int lane = threadIdx.x & 63;
    const int wave = threadIdx.x >> 6;
    const int nw   = blockDim.x >> 6;
    __syncthreads();
    if (lane == 0) sh[wave] = v;
    __syncthreads();
    double r = (threadIdx.x < nw) ? sh[threadIdx.x] : 0.0;
    if (wave == 0) {
#pragma unroll
        for (int o = 8; o > 0; o >>= 1) r += __shfl_down(r, o, 64);
    }
    return r;  // valid in thread 0
}

__device__ inline void process4(float4 s, float4 t, float4 u,
                                unsigned int* myh, float& ent, unsigned int& cnt)
{
    float sv[4] = {s.x, s.y, s.z, s.w};
    float tv[4] = {t.x, t.y, t.z, t.w};
    float uv[4] = {u.x, u.y, u.z, u.w};
#pragma unroll
    for (int k = 0; k < 4; ++k) {
        float topo = 1.0f - fabsf(sv[k] - tv[k]);   // (0, 1]
        float conf = 1.0f - uv[k];                  // (0, 1]
        int ti = (int)(topo * 32.0f);               // exact binning (edges = k/32)
        int ci = (int)(conf * 32.0f);
        if (ti < NBINS && ci < NBINS)
            atomicAdd(&myh[(ti << 5) + ci], 1u);
        bool hc = conf > 0.8f;
        float tc = fminf(fmaxf(topo, 1e-8f), 1.0f - 1e-8f);
        float e  = -tc * __logf(tc + 1e-8f);
        ent += hc ? e : 0.0f;
        cnt += hc ? 1u : 0u;
    }
}

// __launch_bounds__(256,4): 4 waves/SIMD -> <=128 VGPR budget; matches 4 blocks/CU.
extern "C" __global__ void __launch_bounds__(256, 4)
topo_hist_kernel(const float* __restrict__ stu, const float* __restrict__ tea,
                 const float* __restrict__ unc,
                 unsigned int* __restrict__ hist_part,
                 double* __restrict__ ent_part,
                 unsigned int* __restrict__ cnt_part,
                 int n)
{
    __shared__ unsigned int sh_hist[4 * NB2];   // one 1024-bin sub-hist per wave
    __shared__ double sh_red[4];

    const int wave = threadIdx.x >> 6;
    unsigned int* myh = sh_hist + wave * NB2;

    for (int i = threadIdx.x; i < 4 * NB2; i += blockDim.x) sh_hist[i] = 0u;
    __syncthreads();

    float ent = 0.0f;
    unsigned int cnt = 0;

    const int n4     = n >> 2;
    const int gid    = blockIdx.x * blockDim.x + threadIdx.x;
    const int stride = gridDim.x * blockDim.x;

    const float4* s4 = (const float4*)stu;
    const float4* t4 = (const float4*)tea;
    const float4* u4 = (const float4*)unc;

    int i = gid;
    // Software-pipelined: group = 4 float4 per array. Prologue loads group g0;
    // loop loads g(k+1) into fresh regs while processing g(k); rotate.
    if (i + 3 * stride < n4) {
        float4 s0 = s4[i];              float4 t0 = t4[i];              float4 u0 = u4[i];
        float4 s1 = s4[i + stride];     float4 t1 = t4[i + stride];     float4 u1 = u4[i + stride];
        float4 s2 = s4[i + 2 * stride]; float4 t2 = t4[i + 2 * stride]; float4 u2 = u4[i + 2 * stride];
        float4 s3 = s4[i + 3 * stride]; float4 t3 = t4[i + 3 * stride]; float4 u3 = u4[i + 3 * stride];
        int j = i + 4 * stride;
        for (; j + 3 * stride < n4; j += 4 * stride) {
            // prefetch next group (independent of current processing)
            float4 ns0 = s4[j];              float4 nt0 = t4[j];              float4 nu0 = u4[j];
            float4 ns1 = s4[j + stride];     float4 nt1 = t4[j + stride];     float4 nu1 = u4[j + stride];
            float4 ns2 = s4[j + 2 * stride]; float4 nt2 = t4[j + 2 * stride]; float4 nu2 = u4[j + 2 * stride];
            float4 ns3 = s4[j + 3 * stride]; float4 nt3 = t4[j + 3 * stride]; float4 nu3 = u4[j + 3 * stride];
            // process current group
            process4(s0, t0, u0, myh, ent, cnt);
            process4(s1, t1, u1, myh, ent, cnt);
            process4(s2, t2, u2, myh, ent, cnt);
            process4(s3, t3, u3, myh, ent, cnt);
            // rotate
            s0 = ns0; t0 = nt0; u0 = nu0;
            s1 = ns1; t1 = nt1; u1 = nu1;
            s2 = ns2; t2 = nt2; u2 = nu2;
            s3 = ns3; t3 = nt3; u3 = nu3;
        }
        // epilogue: process last in-flight group
        process4(s0, t0, u0, myh, ent, cnt);
        process4(s1, t1, u1, myh, ent, cnt);
        process4(s2, t2, u2, myh, ent, cnt);
        process4(s3, t3, u3, myh, ent, cnt);
        i = j;
    }
    for (; i < n4; i += stride)
        process4(s4[i], t4[i], u4[i], myh, ent, cnt);
    // scalar tail (no-op for 4096^2)
    for (int j = (n4 << 2) + gid; j < n; j += stride) {
        float topo = 1.0f - fabsf(stu[j] - tea[j]);
        float conf = 1.0f - unc[j];
        int ti = (int)(topo * 32.0f);
        int ci = (int)(conf * 32.0f);
        if (ti < NBINS && ci < NBINS)
            atomicAdd(&myh[(ti << 5) + ci], 1u);
        if (conf > 0.8f) {
            float tc = fminf(fmaxf(topo, 1e-8f), 1.0f - 1e-8f);
            ent += -tc * __logf(tc + 1e-8f);
            cnt++;
        }
    }

    __syncthreads();
    // non-atomic flush: plain coalesced stores of this block's 1024-bin hist
    for (int b = threadIdx.x; b < NB2; b += blockDim.x) {
        unsigned int v = sh_hist[b] + sh_hist[NB2 + b] +
                         sh_hist[2 * NB2 + b] + sh_hist[3 * NB2 + b];
        hist_part[(size_t)blockIdx.x * NB2 + b] = v;
    }

    double es = block_reduce_sum_d((double)ent, sh_red);
    double cs = block_reduce_sum_d((double)cnt, sh_red);
    if (threadIdx.x == 0) {
        ent_part[blockIdx.x] = es;
        cnt_part[blockIdx.x] = (unsigned int)(cs + 0.5);
    }
}

// stage-1 reduce: 128 blocks x 256 threads; block g: slice s=g>>2, bin chunk c=g&3
extern "C" __global__ void __launch_bounds__(256)
topo_reduce_kernel(const unsigned int* __restrict__ hist_part,
                   unsigned int* __restrict__ partial2, int B)
{
    const int g   = blockIdx.x;
    const int s   = g >> 2;
    const int c   = g & 3;
    const int bin = (c << 8) + threadIdx.x;
    unsigned int acc = 0;
    for (int b = s; b < B; b += 32)
        acc += hist_part[(size_t)b * NB2 + bin];
    partial2[s * NB2 + bin] = acc;
}

extern "C" __global__ void __launch_bounds__(1024)
topo_final_kernel(const unsigned int* __restrict__ partial2,
                  const double* __restrict__ ent_part,
                  const unsigned int* __restrict__ cnt_part,
                  int B, float* __restrict__ out)
{
    __shared__ double sh_red[16];
    __shared__ double jp[NB2];
    __shared__ double marg_r[NBINS];
    __shared__ double marg_c[NBINS];
    __shared__ double bcast;

    const int tid = threadIdx.x;

    unsigned int c = 0;
#pragma unroll
    for (int s = 0; s < 32; ++s) c += partial2[s * NB2 + tid];
    double dc = (double)c;

    double total = block_reduce_sum_d(dc, sh_red);
    if (tid == 0) bcast = total;
    __syncthreads();
    total = bcast;

    double p = dc / (total + EPSD);
    jp[tid] = p;
    __syncthreads();

    if (tid < NBINS) {
        double s = 0.0;
        for (int cc = 0; cc < NBINS; ++cc) s += jp[(tid << 5) + cc];
        marg_r[tid] = s;
    } else if (tid < 2 * NBINS) {
        int cc = tid - NBINS;
        double s = 0.0;
        for (int r = 0; r < NBINS; ++r) s += jp[(r << 5) + cc];
        marg_c[cc] = s;
    }
    __syncthreads();

    const int r  = tid >> 5;
    const int cc = tid & 31;
    double term = 0.0;
    if (p > EPSD)
        term = p * log(p / (marg_r[r] * marg_c[cc] + EPSD) + EPSD);
    double mi = block_reduce_sum_d(term, sh_red);

    double ev = (tid < B) ? ent_part[tid] : 0.0;
    double es = block_reduce_sum_d(ev, sh_red);
    double cv = (tid < B) ? (double)cnt_part[tid] : 0.0;
    double cs = block_reduce_sum_d(cv, sh_red);

    if (tid == 0) {
        double mi_v     = (total < EPSD) ? 0.0 : mi;
        double mean     = es / fmax(cs, 1.0);
        double ent_loss = (cs > 10.0) ? mean : 0.0;
        out[0] = (float)(-mi_v + 0.1 * ent_loss);
    }
}

extern "C" void kernel_launch(void* const* d_in, const int* in_sizes, int n_in,
                              void* d_out, int out_size, void* d_ws, size_t ws_size,
                              hipStream_t stream) {
    const float* stu = (const float*)d_in[0];
    const float* tea = (const float*)d_in[1];
    const float* unc = (const float*)d_in[2];
    float* out = (float*)d_out;
    int n = in_sizes[0];

    int B = MAXB;  // 1024 blocks x 256 = 4 blocks/CU
    if (ws_size < WS_NEED) {
        size_t per = NB2 * sizeof(unsigned int);
        size_t fixed = 32 * NB2 * sizeof(unsigned int) + MAXB * (sizeof(double) + sizeof(unsigned int));
        B = (ws_size > fixed) ? (int)((ws_size - fixed) / per) : 1;
        if (B < 1) B = 1;
        if (B > MAXB) B = MAXB;
    }

    unsigned int* hist_part = (unsigned int*)d_ws;
    unsigned int* partial2  = (unsigned int*)((char*)d_ws + OFF_P2);
    double*       ent_part  = (double*)((char*)d_ws + OFF_ENT);
    unsigned int* cnt_part  = (unsigned int*)((char*)d_ws + OFF_CNT);

    topo_hist_kernel<<<B, 256, 0, stream>>>(stu, tea, unc, hist_part, ent_part, cnt_part, n);
    topo_reduce_kernel<<<128, 256, 0, stream>>>(hist_part, partial2, B);
    topo_final_kernel<<<1, 1024, 0, stream>>>(partial2, ent_part, cnt_part, B, out);
}